// Round 2
// baseline (3845.712 us; speedup 1.0000x reference)
//
#include <hip/hip_runtime.h>
#include <hip/hip_bf16.h>
#include <math.h>

#define BB 8
#define SS 1024
#define DD 1024
#define HH 16
#define HDIM 64
#define FFD 4096
#define LL 6
#define MM (BB*SS)

typedef unsigned short u16;
typedef __bf16 bf16x8 __attribute__((ext_vector_type(8)));
typedef float f32x4 __attribute__((ext_vector_type(4)));

__device__ __forceinline__ u16 f2b(float f) {
    union { float f; unsigned u; } x; x.f = f;
    unsigned r = x.u + 0x7fffu + ((x.u >> 16) & 1u);
    return (u16)(r >> 16);
}

__device__ __forceinline__ f32x4 mfma16(bf16x8 a, bf16x8 b, f32x4 c) {
    return __builtin_amdgcn_mfma_f32_16x16x32_bf16(a, b, c, 0, 0, 0);
}

__device__ __forceinline__ void async16(const u16* g, char* lds) {
    __builtin_amdgcn_global_load_lds(
        (const __attribute__((address_space(1))) void*)g,
        (__attribute__((address_space(3))) void*)lds, 16, 0, 0);
}

// ---------------- embedding + sinusoidal PE ----------------
__global__ __launch_bounds__(256) void embed_pe_kernel(
        const int* __restrict__ src, const float* __restrict__ emb,
        float* __restrict__ xout, u16* __restrict__ xb) {
    int row = blockIdx.x;           // b*S + s
    int s = row & (SS - 1);
    int tok = src[row];
    int c0 = threadIdx.x * 4;
    const float4 e = *(const float4*)(emb + (size_t)tok * DD + c0);
    float o[4] = {e.x, e.y, e.z, e.w};
    #pragma unroll
    for (int i = 0; i < 4; ++i) {
        int c = c0 + i;
        int j = c & ~1;
        float div = powf(10000.0f, (float)j / (float)DD);
        float arg = (float)s / div;
        float pe = (c & 1) ? cosf(arg) : sinf(arg);
        o[i] = o[i] * 32.0f + pe;   // sqrt(D)=32
    }
    float4 ov = {o[0], o[1], o[2], o[3]};
    *(float4*)(xout + (size_t)row * DD + c0) = ov;
    u16 pk[4] = {f2b(o[0]), f2b(o[1]), f2b(o[2]), f2b(o[3])};
    uint2 pv; __builtin_memcpy(&pv, pk, 8);
    *(uint2*)(xb + (size_t)row * DD + c0) = pv;
}

// ---------------- transpose + f32->bf16 : in[R][C] -> out[C][R] ----------------
__global__ __launch_bounds__(256) void transpose_cvt_kernel(
        const float* __restrict__ in, u16* __restrict__ out, int R, int C) {
    __shared__ float tile[32][33];
    int c0 = blockIdx.x * 32, r0 = blockIdx.y * 32;
    int tx = threadIdx.x & 31, ty = threadIdx.x >> 5;  // ty: 0..7
    #pragma unroll
    for (int i = 0; i < 4; ++i) {
        int r = ty + i * 8;
        tile[r][tx] = in[(size_t)(r0 + r) * C + c0 + tx];
    }
    __syncthreads();
    #pragma unroll
    for (int i = 0; i < 4; ++i) {
        int rr = ty + i * 8;
        out[(size_t)(c0 + rr) * R + r0 + tx] = f2b(tile[tx][rr]);
    }
}

// ---------------- 128x128 bf16 MFMA GEMM, Bt is [N][K] ----------------
// MODE 0: f32 out + bias; 1: bf16 out + bias; 2: bf16 out + bias + relu;
// MODE 3: bf16 out + bias, scattered to V^T layout [(b*H+h)*64+d][S]
template <int MODE>
__global__ __launch_bounds__(256) void gemm_bt(
        const u16* __restrict__ A, const u16* __restrict__ Bt,
        const float* __restrict__ bias, void* __restrict__ Cp,
        int M, int N, int K) {
    __shared__ __align__(16) u16 Al[2][128 * 32];
    __shared__ __align__(16) u16 Bl[2][128 * 32];
    int t = threadIdx.x;
    int w = t >> 6, lane = t & 63, lg = lane >> 4, lr = lane & 15;
    int wr = w >> 1, wc = w & 1;
    int row0 = blockIdx.y * 128, col0 = blockIdx.x * 128;

    f32x4 acc[4][4];
    #pragma unroll
    for (int m = 0; m < 4; ++m)
        #pragma unroll
        for (int n = 0; n < 4; ++n) acc[m][n] = (f32x4){0.f, 0.f, 0.f, 0.f};

    const u16* ag = A + (size_t)(row0 + (t >> 2)) * K + (t & 3) * 8;
    const u16* bg = Bt + (size_t)(col0 + (t >> 2)) * K + (t & 3) * 8;

    auto stage = [&](int buf, int k0) {
        char* adst = (char*)(&Al[buf][0]) + w * 1024;
        char* bdst = (char*)(&Bl[buf][0]) + w * 1024;
        async16(ag + k0, adst);
        async16(ag + (size_t)64 * K + k0, adst + 4096);
        async16(bg + k0, bdst);
        async16(bg + (size_t)64 * K + k0, bdst + 4096);
    };

    stage(0, 0);
    int nt = K >> 5;
    for (int kt = 0; kt < nt; ++kt) {
        __syncthreads();
        int cur = kt & 1;
        if (kt + 1 < nt) stage(cur ^ 1, (kt + 1) << 5);
        bf16x8 af[4], bf[4];
        #pragma unroll
        for (int m = 0; m < 4; ++m)
            af[m] = *(const bf16x8*)&Al[cur][(wr * 64 + m * 16 + lr) * 32 + lg * 8];
        #pragma unroll
        for (int n = 0; n < 4; ++n)
            bf[n] = *(const bf16x8*)&Bl[cur][(wc * 64 + n * 16 + lr) * 32 + lg * 8];
        #pragma unroll
        for (int m = 0; m < 4; ++m)
            #pragma unroll
            for (int n = 0; n < 4; ++n)
                acc[m][n] = mfma16(af[m], bf[n], acc[m][n]);
    }

    float* Cf = (float*)Cp;
    u16* Cb = (u16*)Cp;
    #pragma unroll
    for (int n = 0; n < 4; ++n) {
        int col = col0 + wc * 64 + n * 16 + lr;
        float bn = bias[col];
        #pragma unroll
        for (int m = 0; m < 4; ++m) {
            int rowb = row0 + wr * 64 + m * 16 + lg * 4;
            f32x4 a = acc[m][n];
            if (MODE == 3) {
                u16 pk[4];
                #pragma unroll
                for (int r = 0; r < 4; ++r) pk[r] = f2b(a[r] + bn);
                int b = rowb >> 10, s = rowb & (SS - 1);
                int hh = col >> 6, d = col & (HDIM - 1);
                uint2 pv; __builtin_memcpy(&pv, pk, 8);
                *(uint2*)(Cb + (size_t)((b * HH + hh) * HDIM + d) * SS + s) = pv;
            } else {
                #pragma unroll
                for (int r = 0; r < 4; ++r) {
                    float val = a[r] + bn;
                    size_t idx = (size_t)(rowb + r) * N + col;
                    if (MODE == 0) Cf[idx] = val;
                    else if (MODE == 1) Cb[idx] = f2b(val);
                    else Cb[idx] = f2b(fmaxf(val, 0.0f));
                }
            }
        }
    }
}

// ---------------- flash attention: 4 waves, 16 q-rows/wave ----------------
__global__ __launch_bounds__(256) void attn_kernel(
        const u16* __restrict__ q, const u16* __restrict__ k,
        const u16* __restrict__ vt, const int* __restrict__ mask,
        u16* __restrict__ ctx) {
    __shared__ __align__(16) u16 plds[4][16][72];   // 64 cols + 8 pad
    int w = threadIdx.x >> 6, lane = threadIdx.x & 63;
    int lg = lane >> 4, lr = lane & 15;
    int qt = blockIdx.x, bh = blockIdx.y;
    int b = bh >> 4, h = bh & 15;
    int q0 = qt * 64 + w * 16;

    const u16* qbase = q + (size_t)(b * SS + q0 + lr) * DD + h * HDIM + lg * 8;
    bf16x8 qf0 = *(const bf16x8*)qbase;
    bf16x8 qf1 = *(const bf16x8*)(qbase + 32);

    float mrun[4], ssum[4];
    f32x4 acc[4];
    #pragma unroll
    for (int r = 0; r < 4; ++r) { mrun[r] = -1e30f; ssum[r] = 0.f; }
    #pragma unroll
    for (int n = 0; n < 4; ++n) acc[n] = (f32x4){0.f, 0.f, 0.f, 0.f};
    u16 (*pl)[72] = plds[w];

    for (int k0 = 0; k0 < SS; k0 += 64) {
        f32x4 sc[4];
        #pragma unroll
        for (int f = 0; f < 4; ++f) {
            const u16* kb = k + (size_t)(b * SS + k0 + f * 16 + lr) * DD + h * HDIM + lg * 8;
            bf16x8 kf0 = *(const bf16x8*)kb;
            bf16x8 kf1 = *(const bf16x8*)(kb + 32);
            f32x4 z = (f32x4){0.f, 0.f, 0.f, 0.f};
            z = mfma16(qf0, kf0, z);
            z = mfma16(qf1, kf1, z);
            sc[f] = z;
        }
        float sv[4][4];
        #pragma unroll
        for (int f = 0; f < 4; ++f) {
            bool msk = (mask[b * SS + k0 + f * 16 + lr] == 0);
            #pragma unroll
            for (int r = 0; r < 4; ++r)
                sv[f][r] = msk ? -1e10f : sc[f][r] * 0.125f;
        }
        float mn[4], al[4], ls[4];
        #pragma unroll
        for (int r = 0; r < 4; ++r) {
            float v = fmaxf(fmaxf(sv[0][r], sv[1][r]), fmaxf(sv[2][r], sv[3][r]));
            v = fmaxf(v, __shfl_xor(v, 1));
            v = fmaxf(v, __shfl_xor(v, 2));
            v = fmaxf(v, __shfl_xor(v, 4));
            v = fmaxf(v, __shfl_xor(v, 8));
            mn[r] = fmaxf(mrun[r], v);
            al[r] = __expf(mrun[r] - mn[r]);
            mrun[r] = mn[r];
            ls[r] = 0.f;
        }
        #pragma unroll
        for (int f = 0; f < 4; ++f)
            #pragma unroll
            for (int r = 0; r < 4; ++r) {
                float p = __expf(sv[f][r] - mn[r]);
                ls[r] += p;
                pl[lg * 4 + r][f * 16 + lr] = f2b(p);
            }
        #pragma unroll
        for (int r = 0; r < 4; ++r) {
            float v = ls[r];
            v += __shfl_xor(v, 1); v += __shfl_xor(v, 2);
            v += __shfl_xor(v, 4); v += __shfl_xor(v, 8);
            ssum[r] = ssum[r] * al[r] + v;
        }
        #pragma unroll
        for (int n = 0; n < 4; ++n)
            #pragma unroll
            for (int r = 0; r < 4; ++r) acc[n][r] *= al[r];
        #pragma unroll
        for (int c = 0; c < 2; ++c) {
            bf16x8 pf = *(const bf16x8*)&pl[lr][c * 32 + lg * 8];
            #pragma unroll
            for (int n = 0; n < 4; ++n) {
                const u16* vb = vt + (size_t)(bh * HDIM + n * 16 + lr) * SS + k0 + c * 32 + lg * 8;
                bf16x8 vf = *(const bf16x8*)vb;
                acc[n] = mfma16(pf, vf, acc[n]);
            }
        }
    }
    #pragma unroll
    for (int n = 0; n < 4; ++n)
        #pragma unroll
        for (int r = 0; r < 4; ++r) {
            float o = acc[n][r] / ssum[r];
            ctx[(size_t)(b * SS + q0 + lg * 4 + r) * DD + h * HDIM + n * 16 + lr] = f2b(o);
        }
}

// ---------------- residual add + LayerNorm (in-place f32 x) + bf16 copy ----------------
__global__ __launch_bounds__(256) void ln_kernel(
        float* __restrict__ x, const float* __restrict__ proj,
        const float* __restrict__ g, const float* __restrict__ bb,
        u16* __restrict__ xb) {
    int row = blockIdx.x, t = threadIdx.x;
    size_t base = (size_t)row * DD + t * 4;
    float4 xv = *(const float4*)(x + base);
    float4 pv = *(const float4*)(proj + base);
    float r0 = xv.x + pv.x, r1 = xv.y + pv.y, r2 = xv.z + pv.z, r3 = xv.w + pv.w;
    float s1 = r0 + r1 + r2 + r3;
    float s2 = r0 * r0 + r1 * r1 + r2 * r2 + r3 * r3;
    #pragma unroll
    for (int off = 1; off < 64; off <<= 1) {
        s1 += __shfl_xor(s1, off);
        s2 += __shfl_xor(s2, off);
    }
    __shared__ float a1[4], a2[4];
    int w = t >> 6, lane = t & 63;
    if (lane == 0) { a1[w] = s1; a2[w] = s2; }
    __syncthreads();
    s1 = a1[0] + a1[1] + a1[2] + a1[3];
    s2 = a2[0] + a2[1] + a2[2] + a2[3];
    float mu = s1 * (1.0f / DD);
    float var = s2 * (1.0f / DD) - mu * mu;
    float rs = rsqrtf(var + 1e-5f);
    float4 gv = *(const float4*)(g + t * 4);
    float4 bv = *(const float4*)(bb + t * 4);
    float o0 = (r0 - mu) * rs * gv.x + bv.x;
    float o1 = (r1 - mu) * rs * gv.y + bv.y;
    float o2 = (r2 - mu) * rs * gv.z + bv.z;
    float o3 = (r3 - mu) * rs * gv.w + bv.w;
    float4 ov = {o0, o1, o2, o3};
    *(float4*)(x + base) = ov;
    u16 pk[4] = {f2b(o0), f2b(o1), f2b(o2), f2b(o3)};
    uint2 pv2; __builtin_memcpy(&pv2, pk, 8);
    *(uint2*)(xb + base) = pv2;
}

extern "C" void kernel_launch(void* const* d_in, const int* in_sizes, int n_in,
                              void* d_out, int out_size, void* d_ws, size_t ws_size,
                              hipStream_t stream) {
    const int*   src  = (const int*)d_in[0];
    const int*   mask = (const int*)d_in[1];
    const float* emb  = (const float*)d_in[2];
    const float* Wq   = (const float*)d_in[3];
    const float* bq   = (const float*)d_in[4];
    const float* Wk   = (const float*)d_in[5];
    const float* bk   = (const float*)d_in[6];
    const float* Wv   = (const float*)d_in[7];
    const float* bv   = (const float*)d_in[8];
    const float* Wo   = (const float*)d_in[9];
    const float* bo   = (const float*)d_in[10];
    const float* g1   = (const float*)d_in[11];
    const float* be1  = (const float*)d_in[12];
    const float* W1   = (const float*)d_in[13];
    const float* b1   = (const float*)d_in[14];
    const float* W2   = (const float*)d_in[15];
    const float* b2   = (const float*)d_in[16];
    const float* g2   = (const float*)d_in[17];
    const float* be2  = (const float*)d_in[18];
    (void)in_sizes; (void)n_in; (void)out_size; (void)ws_size;

    float* x = (float*)d_out;
    char* ws = (char*)d_ws;
    const size_t MiB = 1024 * 1024;
    u16* xb   = (u16*)(ws + 0);
    u16* qb   = (u16*)(ws + 16 * MiB);
    u16* kb   = (u16*)(ws + 32 * MiB);
    u16* vtb  = (u16*)(ws + 48 * MiB);
    u16* ctx  = (u16*)(ws + 64 * MiB);
    u16* ffh  = (u16*)(ws + 16 * MiB);   // overlays qb..ctx (dead during FF)
    float* proj = (float*)(ws + 80 * MiB);
    u16* wqT  = (u16*)(ws + 112 * MiB);
    u16* wkT  = (u16*)(ws + 114 * MiB);
    u16* wvT  = (u16*)(ws + 116 * MiB);
    u16* woT  = (u16*)(ws + 118 * MiB);
    u16* w1T  = (u16*)(ws + 120 * MiB);
    u16* w2T  = (u16*)(ws + 128 * MiB);

    embed_pe_kernel<<<MM, 256, 0, stream>>>(src, emb, x, xb);

    for (int l = 0; l < LL; ++l) {
        transpose_cvt_kernel<<<dim3(32, 32), 256, 0, stream>>>(Wq + (size_t)l * DD * DD, wqT, DD, DD);
        transpose_cvt_kernel<<<dim3(32, 32), 256, 0, stream>>>(Wk + (size_t)l * DD * DD, wkT, DD, DD);
        transpose_cvt_kernel<<<dim3(32, 32), 256, 0, stream>>>(Wv + (size_t)l * DD * DD, wvT, DD, DD);
        transpose_cvt_kernel<<<dim3(32, 32), 256, 0, stream>>>(Wo + (size_t)l * DD * DD, woT, DD, DD);
        transpose_cvt_kernel<<<dim3(128, 32), 256, 0, stream>>>(W1 + (size_t)l * DD * FFD, w1T, DD, FFD);
        transpose_cvt_kernel<<<dim3(32, 128), 256, 0, stream>>>(W2 + (size_t)l * FFD * DD, w2T, FFD, DD);

        gemm_bt<1><<<dim3(8, 64), 256, 0, stream>>>(xb, wqT, bq + l * DD, qb, MM, DD, DD);
        gemm_bt<1><<<dim3(8, 64), 256, 0, stream>>>(xb, wkT, bk + l * DD, kb, MM, DD, DD);
        gemm_bt<3><<<dim3(8, 64), 256, 0, stream>>>(xb, wvT, bv + l * DD, vtb, MM, DD, DD);
        attn_kernel<<<dim3(16, 128), 256, 0, stream>>>(qb, kb, vtb, mask, ctx);
        gemm_bt<0><<<dim3(8, 64), 256, 0, stream>>>(ctx, woT, bo + l * DD, proj, MM, DD, DD);
        ln_kernel<<<MM, 256, 0, stream>>>(x, proj, g1 + l * DD, be1 + l * DD, xb);
        gemm_bt<2><<<dim3(32, 64), 256, 0, stream>>>(xb, w1T, b1 + l * FFD, ffh, MM, FFD, DD);
        gemm_bt<0><<<dim3(8, 64), 256, 0, stream>>>(ffh, w2T, b2 + l * DD, proj, MM, DD, FFD);
        ln_kernel<<<MM, 256, 0, stream>>>(x, proj, g2 + l * DD, be2 + l * DD, xb);
    }
}

// Round 3
// 3786.995 us; speedup vs baseline: 1.0155x; 1.0155x over previous
//
#include <hip/hip_runtime.h>
#include <hip/hip_bf16.h>
#include <math.h>

#define BB 8
#define SS 1024
#define DD 1024
#define HH 16
#define HDIM 64
#define FFD 4096
#define LL 6
#define MM (BB*SS)

typedef unsigned short u16;
typedef __bf16 bf16x8 __attribute__((ext_vector_type(8)));
typedef float f32x4 __attribute__((ext_vector_type(4)));

__device__ __forceinline__ u16 f2b(float f) {
    union { float f; unsigned u; } x; x.f = f;
    unsigned r = x.u + 0x7fffu + ((x.u >> 16) & 1u);
    return (u16)(r >> 16);
}

__device__ __forceinline__ f32x4 mfma16(bf16x8 a, bf16x8 b, f32x4 c) {
    return __builtin_amdgcn_mfma_f32_16x16x32_bf16(a, b, c, 0, 0, 0);
}

__device__ __forceinline__ void async16(const u16* g, char* lds) {
    __builtin_amdgcn_global_load_lds(
        (const __attribute__((address_space(1))) void*)g,
        (__attribute__((address_space(3))) void*)lds, 16, 0, 0);
}

// ---------------- embedding + sinusoidal PE ----------------
__global__ __launch_bounds__(256) void embed_pe_kernel(
        const int* __restrict__ src, const float* __restrict__ emb,
        float* __restrict__ xout, u16* __restrict__ xb) {
    int row = blockIdx.x;           // b*S + s
    int s = row & (SS - 1);
    int tok = src[row];
    int c0 = threadIdx.x * 4;
    const float4 e = *(const float4*)(emb + (size_t)tok * DD + c0);
    float o[4] = {e.x, e.y, e.z, e.w};
    #pragma unroll
    for (int i = 0; i < 4; ++i) {
        int c = c0 + i;
        int j = c & ~1;
        float div = powf(10000.0f, (float)j / (float)DD);
        float arg = (float)s / div;
        float pe = (c & 1) ? cosf(arg) : sinf(arg);
        o[i] = o[i] * 32.0f + pe;   // sqrt(D)=32
    }
    float4 ov = {o[0], o[1], o[2], o[3]};
    *(float4*)(xout + (size_t)row * DD + c0) = ov;
    u16 pk[4] = {f2b(o[0]), f2b(o[1]), f2b(o[2]), f2b(o[3])};
    uint2 pv; __builtin_memcpy(&pv, pk, 8);
    *(uint2*)(xb + (size_t)row * DD + c0) = pv;
}

// ---------------- transpose + f32->bf16 : in[R][C] -> out[C][R] ----------------
__global__ __launch_bounds__(256) void transpose_cvt_kernel(
        const float* __restrict__ in, u16* __restrict__ out, int R, int C) {
    __shared__ float tile[32][33];
    int c0 = blockIdx.x * 32, r0 = blockIdx.y * 32;
    int tx = threadIdx.x & 31, ty = threadIdx.x >> 5;  // ty: 0..7
    #pragma unroll
    for (int i = 0; i < 4; ++i) {
        int r = ty + i * 8;
        tile[r][tx] = in[(size_t)(r0 + r) * C + c0 + tx];
    }
    __syncthreads();
    #pragma unroll
    for (int i = 0; i < 4; ++i) {
        int rr = ty + i * 8;
        out[(size_t)(c0 + rr) * R + r0 + tx] = f2b(tile[tx][rr]);
    }
}

// ---------------- 128x128 bf16 MFMA GEMM, Bt is [N][K] ----------------
// MODE 0: f32 out + bias; 1: bf16 out + bias; 2: bf16 out + bias + relu;
// MODE 3: bf16 out + bias, scattered to V^T layout [(b*H+h)*64+d][S]
template <int MODE>
__global__ __launch_bounds__(256) void gemm_bt(
        const u16* __restrict__ A, const u16* __restrict__ Bt,
        const float* __restrict__ bias, void* __restrict__ Cp,
        int M, int N, int K) {
    __shared__ __align__(16) u16 Al[2][128 * 32];
    __shared__ __align__(16) u16 Bl[2][128 * 32];
    int t = threadIdx.x;
    int w = t >> 6, lane = t & 63, lg = lane >> 4, lr = lane & 15;
    int wr = w >> 1, wc = w & 1;
    int row0 = blockIdx.y * 128, col0 = blockIdx.x * 128;

    f32x4 acc[4][4];
    #pragma unroll
    for (int m = 0; m < 4; ++m)
        #pragma unroll
        for (int n = 0; n < 4; ++n) acc[m][n] = (f32x4){0.f, 0.f, 0.f, 0.f};

    const u16* ag = A + (size_t)(row0 + (t >> 2)) * K + (t & 3) * 8;
    const u16* bg = Bt + (size_t)(col0 + (t >> 2)) * K + (t & 3) * 8;

    auto stage = [&](int buf, int k0) {
        char* adst = (char*)(&Al[buf][0]) + w * 1024;
        char* bdst = (char*)(&Bl[buf][0]) + w * 1024;
        async16(ag + k0, adst);
        async16(ag + (size_t)64 * K + k0, adst + 4096);
        async16(bg + k0, bdst);
        async16(bg + (size_t)64 * K + k0, bdst + 4096);
    };

    stage(0, 0);
    int nt = K >> 5;
    for (int kt = 0; kt < nt; ++kt) {
        __syncthreads();
        int cur = kt & 1;
        if (kt + 1 < nt) stage(cur ^ 1, (kt + 1) << 5);
        bf16x8 af[4], bf[4];
        #pragma unroll
        for (int m = 0; m < 4; ++m)
            af[m] = *(const bf16x8*)&Al[cur][(wr * 64 + m * 16 + lr) * 32 + lg * 8];
        #pragma unroll
        for (int n = 0; n < 4; ++n)
            bf[n] = *(const bf16x8*)&Bl[cur][(wc * 64 + n * 16 + lr) * 32 + lg * 8];
        #pragma unroll
        for (int m = 0; m < 4; ++m)
            #pragma unroll
            for (int n = 0; n < 4; ++n)
                acc[m][n] = mfma16(af[m], bf[n], acc[m][n]);
    }

    float* Cf = (float*)Cp;
    u16* Cb = (u16*)Cp;
    #pragma unroll
    for (int n = 0; n < 4; ++n) {
        int col = col0 + wc * 64 + n * 16 + lr;
        float bn = bias[col];
        #pragma unroll
        for (int m = 0; m < 4; ++m) {
            int rowb = row0 + wr * 64 + m * 16 + lg * 4;
            f32x4 a = acc[m][n];
            if (MODE == 3) {
                u16 pk[4];
                #pragma unroll
                for (int r = 0; r < 4; ++r) pk[r] = f2b(a[r] + bn);
                int b = rowb >> 10, s = rowb & (SS - 1);
                int hh = col >> 6, d = col & (HDIM - 1);
                uint2 pv; __builtin_memcpy(&pv, pk, 8);
                *(uint2*)(Cb + (size_t)((b * HH + hh) * HDIM + d) * SS + s) = pv;
            } else {
                #pragma unroll
                for (int r = 0; r < 4; ++r) {
                    float val = a[r] + bn;
                    size_t idx = (size_t)(rowb + r) * N + col;
                    if (MODE == 0) Cf[idx] = val;
                    else if (MODE == 1) Cb[idx] = f2b(val);
                    else Cb[idx] = f2b(fmaxf(val, 0.0f));
                }
            }
        }
    }
}

// ---------------- flash attention v2: 4 waves, 32 q-rows/wave, K reg-dbuf ----------------
__global__ __launch_bounds__(256) void attn_kernel(
        const u16* __restrict__ q, const u16* __restrict__ k,
        const u16* __restrict__ vt, const int* __restrict__ mask,
        u16* __restrict__ ctx) {
    __shared__ __align__(16) u16 plds[4][2][16][72];   // per-wave, per-m: 64 cols + 8 pad
    int w = threadIdx.x >> 6, lane = threadIdx.x & 63;
    int lg = lane >> 4, lr = lane & 15;
    int qt = blockIdx.x, bh = blockIdx.y;
    int b = bh >> 4, h = bh & 15;
    int q0 = qt * 128 + w * 32;

    bf16x8 qf[2][2];
    #pragma unroll
    for (int m = 0; m < 2; ++m) {
        const u16* qb = q + (size_t)(b * SS + q0 + m * 16 + lr) * DD + h * HDIM + lg * 8;
        qf[m][0] = *(const bf16x8*)qb;
        qf[m][1] = *(const bf16x8*)(qb + 32);
    }

    float mrun[2][4], ssum[2][4];
    f32x4 acc[2][4];
    #pragma unroll
    for (int m = 0; m < 2; ++m) {
        #pragma unroll
        for (int r = 0; r < 4; ++r) { mrun[m][r] = -1e30f; ssum[m][r] = 0.f; }
        #pragma unroll
        for (int n = 0; n < 4; ++n) acc[m][n] = (f32x4){0.f, 0.f, 0.f, 0.f};
    }

    const u16* kbase = k + (size_t)(b * SS + lr) * DD + h * HDIM + lg * 8;
    const u16* vbase = vt + (size_t)(bh * HDIM + lr) * SS + lg * 8;
    const int* mbase = mask + b * SS + lr;

    auto loadK = [&](bf16x8 (&kr)[4][2], int k0) {
        #pragma unroll
        for (int f = 0; f < 4; ++f) {
            const u16* p = kbase + (size_t)(k0 + f * 16) * DD;
            kr[f][0] = *(const bf16x8*)p;
            kr[f][1] = *(const bf16x8*)(p + 32);
        }
    };

    auto step = [&](bf16x8 (&kc)[4][2], bf16x8 (&kn)[4][2], int t, bool pre) {
        int k0 = t * 64;
        if (pre) loadK(kn, k0 + 64);        // next-tile K: latency hides under this tile
        // QK^T for both q-row fragments (shared K)
        f32x4 sc[2][4];
        #pragma unroll
        for (int m = 0; m < 2; ++m)
            #pragma unroll
            for (int f = 0; f < 4; ++f) {
                f32x4 z = (f32x4){0.f, 0.f, 0.f, 0.f};
                z = mfma16(qf[m][0], kc[f][0], z);
                z = mfma16(qf[m][1], kc[f][1], z);
                sc[m][f] = z;
            }
        // V loads for THIS tile: issue now, consumed after softmax (~400cy cover)
        bf16x8 vr[4][2];
        #pragma unroll
        for (int n = 0; n < 4; ++n)
            #pragma unroll
            for (int c = 0; c < 2; ++c)
                vr[n][c] = *(const bf16x8*)(vbase + (size_t)(n * 16) * SS + k0 + c * 32);
        int mk[4];
        #pragma unroll
        for (int f = 0; f < 4; ++f) mk[f] = mbase[k0 + f * 16];
        // online softmax, two independent chains (m=0,1)
        #pragma unroll
        for (int m = 0; m < 2; ++m) {
            float sv[4][4];
            #pragma unroll
            for (int f = 0; f < 4; ++f) {
                bool msk = (mk[f] == 0);
                #pragma unroll
                for (int r = 0; r < 4; ++r)
                    sv[f][r] = msk ? -1e10f : sc[m][f][r] * 0.125f;
            }
            float mn[4], al[4], ls[4];
            #pragma unroll
            for (int r = 0; r < 4; ++r) {
                float v = fmaxf(fmaxf(sv[0][r], sv[1][r]), fmaxf(sv[2][r], sv[3][r]));
                v = fmaxf(v, __shfl_xor(v, 1));
                v = fmaxf(v, __shfl_xor(v, 2));
                v = fmaxf(v, __shfl_xor(v, 4));
                v = fmaxf(v, __shfl_xor(v, 8));
                mn[r] = fmaxf(mrun[m][r], v);
                al[r] = __expf(mrun[m][r] - mn[r]);
                mrun[m][r] = mn[r];
                ls[r] = 0.f;
            }
            #pragma unroll
            for (int f = 0; f < 4; ++f)
                #pragma unroll
                for (int r = 0; r < 4; ++r) {
                    float p = __expf(sv[f][r] - mn[r]);
                    ls[r] += p;
                    plds[w][m][lg * 4 + r][f * 16 + lr] = f2b(p);
                }
            #pragma unroll
            for (int r = 0; r < 4; ++r) {
                float v = ls[r];
                v += __shfl_xor(v, 1); v += __shfl_xor(v, 2);
                v += __shfl_xor(v, 4); v += __shfl_xor(v, 8);
                ssum[m][r] = ssum[m][r] * al[r] + v;
            }
            #pragma unroll
            for (int n = 0; n < 4; ++n)
                #pragma unroll
                for (int r = 0; r < 4; ++r) acc[m][n][r] *= al[r];
        }
        // PV (V regs already landed)
        #pragma unroll
        for (int m = 0; m < 2; ++m)
            #pragma unroll
            for (int c = 0; c < 2; ++c) {
                bf16x8 pf = *(const bf16x8*)&plds[w][m][lr][c * 32 + lg * 8];
                #pragma unroll
                for (int n = 0; n < 4; ++n)
                    acc[m][n] = mfma16(pf, vr[n][c], acc[m][n]);
            }
    };

    bf16x8 kA[4][2], kB[4][2];
    loadK(kA, 0);
    for (int tt = 0; tt < 7; ++tt) {        // runtime loop: 2 inlined steps, static regs
        step(kA, kB, 2 * tt, true);
        step(kB, kA, 2 * tt + 1, true);
    }
    step(kA, kB, 14, true);
    step(kB, kA, 15, false);

    #pragma unroll
    for (int m = 0; m < 2; ++m) {
        float rin[4];
        #pragma unroll
        for (int r = 0; r < 4; ++r) rin[r] = 1.0f / ssum[m][r];
        #pragma unroll
        for (int n = 0; n < 4; ++n)
            #pragma unroll
            for (int r = 0; r < 4; ++r) {
                float o = acc[m][n][r] * rin[r];
                ctx[(size_t)(b * SS + q0 + m * 16 + lg * 4 + r) * DD + h * HDIM + n * 16 + lr] = f2b(o);
            }
    }
}

// ---------------- residual add + LayerNorm (in-place f32 x) + bf16 copy ----------------
__global__ __launch_bounds__(256) void ln_kernel(
        float* __restrict__ x, const float* __restrict__ proj,
        const float* __restrict__ g, const float* __restrict__ bb,
        u16* __restrict__ xb) {
    int row = blockIdx.x, t = threadIdx.x;
    size_t base = (size_t)row * DD + t * 4;
    float4 xv = *(const float4*)(x + base);
    float4 pv = *(const float4*)(proj + base);
    float r0 = xv.x + pv.x, r1 = xv.y + pv.y, r2 = xv.z + pv.z, r3 = xv.w + pv.w;
    float s1 = r0 + r1 + r2 + r3;
    float s2 = r0 * r0 + r1 * r1 + r2 * r2 + r3 * r3;
    #pragma unroll
    for (int off = 1; off < 64; off <<= 1) {
        s1 += __shfl_xor(s1, off);
        s2 += __shfl_xor(s2, off);
    }
    __shared__ float a1[4], a2[4];
    int w = t >> 6, lane = t & 63;
    if (lane == 0) { a1[w] = s1; a2[w] = s2; }
    __syncthreads();
    s1 = a1[0] + a1[1] + a1[2] + a1[3];
    s2 = a2[0] + a2[1] + a2[2] + a2[3];
    float mu = s1 * (1.0f / DD);
    float var = s2 * (1.0f / DD) - mu * mu;
    float rs = rsqrtf(var + 1e-5f);
    float4 gv = *(const float4*)(g + t * 4);
    float4 bv = *(const float4*)(bb + t * 4);
    float o0 = (r0 - mu) * rs * gv.x + bv.x;
    float o1 = (r1 - mu) * rs * gv.y + bv.y;
    float o2 = (r2 - mu) * rs * gv.z + bv.z;
    float o3 = (r3 - mu) * rs * gv.w + bv.w;
    float4 ov = {o0, o1, o2, o3};
    *(float4*)(x + base) = ov;
    u16 pk[4] = {f2b(o0), f2b(o1), f2b(o2), f2b(o3)};
    uint2 pv2; __builtin_memcpy(&pv2, pk, 8);
    *(uint2*)(xb + base) = pv2;
}

extern "C" void kernel_launch(void* const* d_in, const int* in_sizes, int n_in,
                              void* d_out, int out_size, void* d_ws, size_t ws_size,
                              hipStream_t stream) {
    const int*   src  = (const int*)d_in[0];
    const int*   mask = (const int*)d_in[1];
    const float* emb  = (const float*)d_in[2];
    const float* Wq   = (const float*)d_in[3];
    const float* bq   = (const float*)d_in[4];
    const float* Wk   = (const float*)d_in[5];
    const float* bk   = (const float*)d_in[6];
    const float* Wv   = (const float*)d_in[7];
    const float* bv   = (const float*)d_in[8];
    const float* Wo   = (const float*)d_in[9];
    const float* bo   = (const float*)d_in[10];
    const float* g1   = (const float*)d_in[11];
    const float* be1  = (const float*)d_in[12];
    const float* W1   = (const float*)d_in[13];
    const float* b1   = (const float*)d_in[14];
    const float* W2   = (const float*)d_in[15];
    const float* b2   = (const float*)d_in[16];
    const float* g2   = (const float*)d_in[17];
    const float* be2  = (const float*)d_in[18];
    (void)in_sizes; (void)n_in; (void)out_size; (void)ws_size;

    float* x = (float*)d_out;
    char* ws = (char*)d_ws;
    const size_t MiB = 1024 * 1024;
    u16* xb   = (u16*)(ws + 0);
    u16* qb   = (u16*)(ws + 16 * MiB);
    u16* kb   = (u16*)(ws + 32 * MiB);
    u16* vtb  = (u16*)(ws + 48 * MiB);
    u16* ctx  = (u16*)(ws + 64 * MiB);
    u16* ffh  = (u16*)(ws + 16 * MiB);   // overlays qb..ctx (dead during FF)
    float* proj = (float*)(ws + 80 * MiB);
    u16* wqT  = (u16*)(ws + 112 * MiB);
    u16* wkT  = (u16*)(ws + 114 * MiB);
    u16* wvT  = (u16*)(ws + 116 * MiB);
    u16* woT  = (u16*)(ws + 118 * MiB);
    u16* w1T  = (u16*)(ws + 120 * MiB);
    u16* w2T  = (u16*)(ws + 128 * MiB);

    embed_pe_kernel<<<MM, 256, 0, stream>>>(src, emb, x, xb);

    for (int l = 0; l < LL; ++l) {
        transpose_cvt_kernel<<<dim3(32, 32), 256, 0, stream>>>(Wq + (size_t)l * DD * DD, wqT, DD, DD);
        transpose_cvt_kernel<<<dim3(32, 32), 256, 0, stream>>>(Wk + (size_t)l * DD * DD, wkT, DD, DD);
        transpose_cvt_kernel<<<dim3(32, 32), 256, 0, stream>>>(Wv + (size_t)l * DD * DD, wvT, DD, DD);
        transpose_cvt_kernel<<<dim3(32, 32), 256, 0, stream>>>(Wo + (size_t)l * DD * DD, woT, DD, DD);
        transpose_cvt_kernel<<<dim3(128, 32), 256, 0, stream>>>(W1 + (size_t)l * DD * FFD, w1T, DD, FFD);
        transpose_cvt_kernel<<<dim3(32, 128), 256, 0, stream>>>(W2 + (size_t)l * FFD * DD, w2T, FFD, DD);

        gemm_bt<1><<<dim3(8, 64), 256, 0, stream>>>(xb, wqT, bq + l * DD, qb, MM, DD, DD);
        gemm_bt<1><<<dim3(8, 64), 256, 0, stream>>>(xb, wkT, bk + l * DD, kb, MM, DD, DD);
        gemm_bt<3><<<dim3(8, 64), 256, 0, stream>>>(xb, wvT, bv + l * DD, vtb, MM, DD, DD);
        attn_kernel<<<dim3(8, 128), 256, 0, stream>>>(qb, kb, vtb, mask, ctx);
        gemm_bt<0><<<dim3(8, 64), 256, 0, stream>>>(ctx, woT, bo + l * DD, proj, MM, DD, DD);
        ln_kernel<<<MM, 256, 0, stream>>>(x, proj, g1 + l * DD, be1 + l * DD, xb);
        gemm_bt<2><<<dim3(32, 64), 256, 0, stream>>>(xb, w1T, b1 + l * FFD, ffh, MM, FFD, DD);
        gemm_bt<0><<<dim3(8, 64), 256, 0, stream>>>(ffh, w2T, b2 + l * DD, proj, MM, DD, FFD);
        ln_kernel<<<MM, 256, 0, stream>>>(x, proj, g2 + l * DD, be2 + l * DD, xb);
    }
}